// Round 19
// baseline (228.794 us; speedup 1.0000x reference)
//
#include <hip/hip_runtime.h>
#include <math.h>

#define NB 4096            // batch
#define DIMX 784           // feature dim for x / y pdists

typedef __attribute__((ext_vector_type(8))) short bf16x8;
typedef __attribute__((ext_vector_type(4))) float f32x4;

__device__ __forceinline__ float lrelu_f(float v) { return v >= 0.f ? v : 0.01f * v; }

// round-to-nearest-even fp32 -> bf16 hi (returned as float), residual -> bf16 lo
__device__ __forceinline__ float split1h(float x, short& hi_s, short& lo_s) {
    unsigned u = __float_as_uint(x);
    unsigned hib = (u + 0x7FFFu + ((u >> 16) & 1u)) & 0xFFFF0000u;
    float hif = __uint_as_float(hib);
    float lo = x - hif;
    unsigned ul = __float_as_uint(lo);
    unsigned lob = (ul + 0x7FFFu + ((ul >> 16) & 1u)) >> 16;
    hi_s = (short)(hib >> 16);
    lo_s = (short)lob;
    return hif;
}

#define GLL(srcp, dstp) __builtin_amdgcn_global_load_lds( \
    (const __attribute__((address_space(1))) void*)(srcp), \
    (__attribute__((address_space(3))) void*)(dstp), 16, 0, 0)

// T2 swizzle (both-sides involution keyed on write-row's (row>>1)&3):
//   256-thr staging (srow=tid>>2): col-block (tid&3)^((tid>>3)&3)
//   512-thr staging (srow=lane>>2): col-block (lane&3)^((lane>>3)&3)
//   read k-slot (lane>>4)^((lane>>1)&3)   [row = 16-aligned + (lane&15)]

// ---------------------------------------------------------------------------
// Prep: [0,3920) weight splits; [3920,8016) x-row split + sqx(from hi) + sqy=0.
// sqx = squared norm of bf16-ROUNDED x row -> hh pdist is exact metric on
// rounded points (error <= ||lo_i||+||lo_j|| ~ 0.03 << threshold).
// ---------------------------------------------------------------------------
__global__ __launch_bounds__(256) void prep_all(
    const float* __restrict__ w1, const float* __restrict__ w11,
    const float* __restrict__ w32, const float* __restrict__ w4,
    short* __restrict__ o1, short* __restrict__ o11,
    short* __restrict__ o32, short* __restrict__ o4,
    const float* __restrict__ X, short* __restrict__ Xs,
    float* __restrict__ sqx, float* __restrict__ sqy)
{
    const int bid = blockIdx.x;
    const int t = threadIdx.x;
    if (bid < 3920) {
        const float* W; short* O; int N, K, NP, KP, base;
        if (bid < 1600)      { W = w1;  O = o1;  N = 400; K = 784; NP = 512; KP = 800; base = 0; }
        else if (bid < 2016) { W = w11; O = o11; N = 200; K = 400; NP = 256; KP = 416; base = 1600; }
        else if (bid < 2464) { W = w32; O = o32; N = 400; K = 200; NP = 512; KP = 224; base = 2016; }
        else                 { W = w4;  O = o4;  N = 784; K = 400; NP = 896; KP = 416; base = 2464; }
        const int idx = (bid - base) * 256 + t;
        if (idx >= NP * KP) return;
        const int r = idx / KP, k = idx - r * KP;
        short hi = 0, lo = 0;
        if (r < N && k < K) split1h(W[(size_t)r * K + k], hi, lo);
        O[(size_t)r * 2 * KP + k]      = hi;
        O[(size_t)r * 2 * KP + KP + k] = lo;
    } else {
        const int r = bid - 3920;
        float s = 0.f;
        if (t < 200) {
            const int k0 = t * 4;
            short h[4] = {0, 0, 0, 0}, l[4] = {0, 0, 0, 0};
            if (k0 < 784) {
                float4 v = *(const float4*)(X + (size_t)r * 784 + k0);
                float h0 = split1h(v.x, h[0], l[0]);
                float h1 = split1h(v.y, h[1], l[1]);
                float h2v = split1h(v.z, h[2], l[2]);
                float h3v = split1h(v.w, h[3], l[3]);
                s = h0 * h0 + h1 * h1 + h2v * h2v + h3v * h3v;   // norm of ROUNDED row
            }
            *(uint2*)&Xs[(size_t)r * 1600 + k0]       = *(const uint2*)h;
            *(uint2*)&Xs[(size_t)r * 1600 + 800 + k0] = *(const uint2*)l;
        }
        __shared__ float red[256];
        red[t] = s;
        __syncthreads();
        for (int off = 128; off > 0; off >>= 1) {
            if (t < off) red[t] += red[t + off];
            __syncthreads();
        }
        if (t == 0) { sqx[r] = red[0]; sqy[r] = 0.f; }
    }
}

// ---------------------------------------------------------------------------
// bf16-split MFMA GEMM, 3-TERM, BM=64 x BN=128 tile (r15-proven).
// HIONLY: split output is hi-only [M][KPo]. WROWSQ: |round(y)|^2 -> sqy.
// ---------------------------------------------------------------------------
template<int ACT, bool WF32, bool WSPLIT, bool WROWSQ, bool HIONLY>
__global__ __launch_bounds__(256) void gemm3_64(
    const short* __restrict__ As_g, const short* __restrict__ Ws_g,
    const float* __restrict__ bias, float* __restrict__ C,
    short* __restrict__ Cs, int N, int KPi, int nchunk, int KPo,
    float* __restrict__ sqy)
{
    __shared__ short L[2][12288];   // 48 KiB: Ah@0 Al@2048 Bh@4096 Bl@8192
    const int tid = threadIdx.x;
    const int w = tid >> 6, lane = tid & 63;
    const int wc = w;
    const int m0 = blockIdx.y * 64, n0 = blockIdx.x * 128;
    const int frow = lane & 15;
    const int fk_sw = (((lane >> 4) ^ ((lane >> 1) & 3))) * 8;
    const int srow = tid >> 2;
    const int scol_sw = (((tid & 3) ^ ((tid >> 3) & 3))) * 8;
    const int RS = 2 * KPi;
    const int ld0 = w * 512;

    const short* gA  = As_g + (size_t)(m0 + srow) * RS + scol_sw;
    const short* gB0 = Ws_g + (size_t)(n0 + srow) * RS + scol_sw;
    const short* gB1 = gB0 + (size_t)64 * RS;

    f32x4 acc[4][2] = {};

    auto stage = [&](int buf, int km) {
        GLL(gA  + km,       &L[buf][ld0]);
        GLL(gA  + KPi + km, &L[buf][2048 + ld0]);
        GLL(gB0 + km,       &L[buf][4096 + ld0]);
        GLL(gB1 + km,       &L[buf][6144 + ld0]);
        GLL(gB0 + KPi + km, &L[buf][8192 + ld0]);
        GLL(gB1 + KPi + km, &L[buf][10240 + ld0]);
    };

    stage(0, 0);
    asm volatile("s_waitcnt vmcnt(0)" ::: "memory");
    __builtin_amdgcn_s_barrier();
    int buf = 0;
    #pragma unroll 1
    for (int cc = 0; cc < nchunk; ++cc) {
        if (cc + 1 < nchunk) {
            stage(buf ^ 1, (cc + 1) * 32);
            asm volatile("s_waitcnt vmcnt(6)" ::: "memory");
        } else {
            asm volatile("s_waitcnt vmcnt(0)" ::: "memory");
        }
        __builtin_amdgcn_s_barrier();

        bf16x8 ah[4], al[4], bh[2], bl[2];
        #pragma unroll
        for (int m = 0; m < 4; ++m) {
            const int ro = (m * 16 + frow) * 32 + fk_sw;
            ah[m] = *(const bf16x8*)&L[buf][ro];
            al[m] = *(const bf16x8*)&L[buf][2048 + ro];
        }
        #pragma unroll
        for (int n = 0; n < 2; ++n) {
            const int ro = (wc * 32 + n * 16 + frow) * 32 + fk_sw;
            bh[n] = *(const bf16x8*)&L[buf][4096 + ro];
            bl[n] = *(const bf16x8*)&L[buf][8192 + ro];
        }
        __builtin_amdgcn_s_setprio(1);
        #pragma unroll
        for (int m = 0; m < 4; ++m)
            #pragma unroll
            for (int n = 0; n < 2; ++n) {
                acc[m][n] = __builtin_amdgcn_mfma_f32_16x16x32_bf16(ah[m], bh[n], acc[m][n], 0, 0, 0);
                acc[m][n] = __builtin_amdgcn_mfma_f32_16x16x32_bf16(ah[m], bl[n], acc[m][n], 0, 0, 0);
                acc[m][n] = __builtin_amdgcn_mfma_f32_16x16x32_bf16(al[m], bh[n], acc[m][n], 0, 0, 0);
            }
        __builtin_amdgcn_s_setprio(0);
        __builtin_amdgcn_s_barrier();
        buf ^= 1;
    }

    const int col0 = lane & 15;
    const int row4 = (lane >> 4) * 4;

    float* rowsum = (float*)&L[0][0];
    if (WROWSQ) {
        __syncthreads();
        if (tid < 64) rowsum[tid] = 0.f;
        __syncthreads();
    }

    #pragma unroll
    for (int m = 0; m < 4; ++m) {
        #pragma unroll
        for (int r = 0; r < 4; ++r) {
            const int gm = m0 + m * 16 + row4 + r;
            float vsq = 0.f;
            #pragma unroll
            for (int n = 0; n < 2; ++n) {
                const int gn = n0 + wc * 32 + n * 16 + col0;
                float v = 0.f;
                if (gn < N) {
                    v = acc[m][n][r] + bias[gn];
                    if (ACT == 1)      v = lrelu_f(v);
                    else if (ACT == 2) v = 1.f / (1.f + expf(-v));
                }
                if (WF32 && gn < N) C[(size_t)gm * N + gn] = v;
                if (WSPLIT && gn < KPo) {
                    short hi, lo;
                    float hif = split1h(v, hi, lo);
                    if (HIONLY) {
                        Cs[(size_t)gm * KPo + gn] = hi;
                    } else {
                        Cs[(size_t)gm * 2 * KPo + gn]       = hi;
                        Cs[(size_t)gm * 2 * KPo + KPo + gn] = lo;
                    }
                    if (WROWSQ) vsq = fmaf(hif, hif, vsq);
                }
            }
            if (WROWSQ) atomicAdd(&rowsum[m * 16 + row4 + r], vsq);
        }
    }
    if (WROWSQ) {
        __syncthreads();
        if (tid < 64) atomicAdd(&sqy[m0 + tid], rowsum[tid]);
    }
}

// ---------------------------------------------------------------------------
// Fused mid-chain: h2 -> h3 -> z -> y1 -> y2s (r10-proven)
// ---------------------------------------------------------------------------
__global__ __launch_bounds__(256) void fused_mid(
    const float* __restrict__ h2, const float* __restrict__ W12,
    const float* __restrict__ b12, const float* __restrict__ W2,
    const float* __restrict__ b2,  const float* __restrict__ W3,
    const float* __restrict__ b3,  const float* __restrict__ W31,
    const float* __restrict__ b31, float* __restrict__ z_out,
    short* __restrict__ y2s)
{
    __shared__ float wbuf[200 * 51];
    __shared__ float hl[16 * 201];
    __shared__ float h3l[16 * 51];
    __shared__ float y1l[16 * 51];
    __shared__ float zl[16 * 2];
    __shared__ float w2l[100], w3l[100];
    __shared__ float b12l[50], b2l[2], b3l[50], b31l[200];
    const int t = threadIdx.x;
    const int r0 = blockIdx.x * 16;

    for (int i = t; i < 50 * 200; i += 256) { int n = i / 200, k = i - n * 200; wbuf[n * 201 + k] = W12[i]; }
    for (int i = t; i < 16 * 200; i += 256) { int r = i / 200, k = i - r * 200; hl[r * 201 + k] = h2[(size_t)(r0 + r) * 200 + k]; }
    for (int i = t; i < 100; i += 256) { w2l[i] = W2[i]; w3l[i] = W3[i]; }
    if (t < 50)  { b12l[t] = b12[t]; b3l[t] = b3[t]; }
    if (t < 2)   b2l[t] = b2[t];
    if (t < 200) b31l[t] = b31[t];
    __syncthreads();

    for (int i = t; i < 16 * 50; i += 256) {
        int r = i / 50, n = i - r * 50;
        float s = b12l[n];
        #pragma unroll 4
        for (int k = 0; k < 200; ++k) s = fmaf(hl[r * 201 + k], wbuf[n * 201 + k], s);
        h3l[r * 51 + n] = tanhf(lrelu_f(s));
    }
    __syncthreads();

    if (t < 32) {
        int r = t >> 1, n = t & 1;
        float s = b2l[n];
        #pragma unroll
        for (int k = 0; k < 50; ++k) s = fmaf(h3l[r * 51 + k], w2l[n * 50 + k], s);
        zl[r * 2 + n] = s;
        z_out[(size_t)(r0 + r) * 2 + n] = s;
    }
    for (int i = t; i < 200 * 50; i += 256) { int n = i / 50, k = i - n * 50; wbuf[n * 51 + k] = W31[i]; }
    __syncthreads();

    for (int i = t; i < 16 * 50; i += 256) {
        int r = i / 50, n = i - r * 50;
        float s = fmaf(zl[r * 2], w3l[n * 2], fmaf(zl[r * 2 + 1], w3l[n * 2 + 1], b3l[n]));
        y1l[r * 51 + n] = lrelu_f(s);
    }
    __syncthreads();

    for (int i = t; i < 16 * 224; i += 256) {
        int r = i / 224, n = i - r * 224;
        float v = 0.f;
        if (n < 200) {
            float s = b31l[n];
            #pragma unroll
            for (int k = 0; k < 50; ++k) s = fmaf(y1l[r * 51 + k], wbuf[n * 51 + k], s);
            v = lrelu_f(s);
        }
        short hi, lo;
        split1h(v, hi, lo);
        const size_t gm = r0 + r;
        y2s[gm * 448 + n]       = hi;
        y2s[gm * 448 + 224 + n] = lo;
    }
}

// ---------------------------------------------------------------------------
// Final pdist, 800 blocks x 512 thr, 64 KiB LDS dbuf:
//   blocks 0..135   : y-side hh 256x256 (ys stride 800, sqy from rounded y)
//   blocks 136..271 : x-side hh 256x256 (xs stride 1600, sqx from rounded x)
//   blocks 272..799 : z-side 128x128 direct difference
// 256^2 tiles halve the L2-staged traffic (the measured ~4.9 TB/s binding
// constraint at 128^2). Body = r8-proven 512-thr heavy structure, hh-only,
// dbuf + counted vmcnt(4), T2 swizzle (512-thr write key (lane>>3)&3).
// ---------------------------------------------------------------------------
__global__ __launch_bounds__(512, 1) void pdist256(
    const short* __restrict__ xs, const short* __restrict__ ys,
    const float* __restrict__ sqx, const float* __restrict__ sqy,
    const float* __restrict__ Z, float* __restrict__ in_diff,
    float* __restrict__ out_diff, float* __restrict__ lat_diff)
{
    __shared__ short L[2][2][8192];   // [buf][A,B][256*32] = 64 KiB
    const int tid = threadIdx.x;
    const int orig = blockIdx.x;

    if (orig < 272) {
        // ================= hh 256x256 tile =================
        const bool isY = (orig < 136);
        const int o = isY ? orig : orig - 136;
        const int b = (o & 7) * 17 + (o >> 3);     // bijective: 136 = 8*17
        int rem = b, ti = 0;
        while (rem >= 16 - ti) { rem -= 16 - ti; ++ti; }
        const int tj = ti + rem;

        const short* Xs = isY ? ys : xs;
        const int rs    = isY ? 800 : 1600;
        const float* sq = isY ? sqy : sqx;
        float* outp     = isY ? out_diff : in_diff;

        const int w = tid >> 6, lane = tid & 63;
        const int wr = w >> 2, wc = w & 3;          // 2x4 waves, wave tile 128x64
        const int frow = lane & 15;
        const int fk_sw = (((lane >> 4) ^ ((lane >> 1) & 3))) * 8;
        const int srow = w * 16 + (lane >> 2);      // 0..127
        const int scol_sw = (((lane & 3) ^ ((lane >> 3) & 3))) * 8;
        const int i0 = ti * 256, j0 = tj * 256;
        const int ld0 = w * 512;

        const short* gA = Xs + (size_t)(i0 + srow) * rs + scol_sw;
        const short* gB = Xs + (size_t)(j0 + srow) * rs + scol_sw;
        const size_t half = (size_t)128 * rs;

        f32x4 acc[8][4] = {};

        auto stage = [&](int buf, int km) {
            GLL(gA + km,        &L[buf][0][ld0]);
            GLL(gA + half + km, &L[buf][0][4096 + ld0]);
            GLL(gB + km,        &L[buf][1][ld0]);
            GLL(gB + half + km, &L[buf][1][4096 + ld0]);
        };

        stage(0, 0);
        asm volatile("s_waitcnt vmcnt(0)" ::: "memory");
        __builtin_amdgcn_s_barrier();
        int buf = 0;
        #pragma unroll 1
        for (int cc = 0; cc < 25; ++cc) {
            if (cc < 24) {
                stage(buf ^ 1, (cc + 1) * 32);
                asm volatile("s_waitcnt vmcnt(4)" ::: "memory");
            } else {
                asm volatile("s_waitcnt vmcnt(0)" ::: "memory");
            }
            __builtin_amdgcn_s_barrier();

            bf16x8 a[8], bb[4];
            #pragma unroll
            for (int m = 0; m < 8; ++m)
                a[m] = *(const bf16x8*)&L[buf][0][(wr * 128 + m * 16 + frow) * 32 + fk_sw];
            #pragma unroll
            for (int n = 0; n < 4; ++n)
                bb[n] = *(const bf16x8*)&L[buf][1][(wc * 64 + n * 16 + frow) * 32 + fk_sw];
            __builtin_amdgcn_s_setprio(1);
            #pragma unroll
            for (int m = 0; m < 8; ++m)
                #pragma unroll
                for (int n = 0; n < 4; ++n)
                    acc[m][n] = __builtin_amdgcn_mfma_f32_16x16x32_bf16(a[m], bb[n], acc[m][n], 0, 0, 0);
            __builtin_amdgcn_s_setprio(0);
            __builtin_amdgcn_s_barrier();
            buf ^= 1;
        }

        const int col0 = lane & 15;
        const int row4 = (lane >> 4) * 4;
        float sqj_v[4];
        #pragma unroll
        for (int n = 0; n < 4; ++n)
            sqj_v[n] = sq[j0 + wc * 64 + n * 16 + col0];

        #pragma unroll
        for (int m = 0; m < 8; ++m) {
            #pragma unroll
            for (int r = 0; r < 4; ++r) {
                const int gi = i0 + wr * 128 + m * 16 + row4 + r;
                const float sqi = sq[gi];
                const int rowbase = (gi * (2 * NB - 1 - gi)) / 2 - gi - 1;
                #pragma unroll
                for (int n = 0; n < 4; ++n) {
                    const int gj = j0 + wc * 64 + n * 16 + col0;
                    if (gj > gi) {
                        float d2 = sqi + sqj_v[n] - 2.f * acc[m][n][r];
                        outp[rowbase + gj] = sqrtf(fmaxf(d2, 0.f));
                    }
                }
            }
        }
    } else {
        // ================= z-pdist: 128x128 direct difference =================
        const int o = orig - 272;
        const int b = (o & 7) * 66 + (o >> 3);     // bijective: 528 = 8*66
        int rem = b, ti = 0;
        while (rem >= 32 - ti) { rem -= 32 - ti; ++ti; }
        const int tj = ti + rem;
        const int i0 = ti * 128, j0 = tj * 128;

        float* zi = (float*)&L[0][0][0];
        float* zj = (float*)&L[0][0][512];
        if (tid < 128) {
            *(float2*)&zi[tid * 2] = *(const float2*)&Z[(size_t)(i0 + tid) * 2];
        } else if (tid < 256) {
            const int r = tid - 128;
            *(float2*)&zj[r * 2] = *(const float2*)&Z[(size_t)(j0 + r) * 2];
        }
        __syncthreads();

        const int ty = tid >> 5;   // 0..15 -> 8 rows each
        const int tx = tid & 31;   // 0..31 -> 4 cols each
        #pragma unroll
        for (int ii = 0; ii < 8; ++ii) {
            const int li = ty * 8 + ii;
            const int gi = i0 + li;
            const int rowbase = (gi * (2 * NB - 1 - gi)) / 2 - gi - 1;
            const float zi0 = zi[li * 2], zi1 = zi[li * 2 + 1];
            #pragma unroll
            for (int jj = 0; jj < 4; ++jj) {
                const int lj = tx * 4 + jj;
                const int gj = j0 + lj;
                if (gj > gi) {
                    float d0 = zi0 - zj[lj * 2];
                    float d1 = zi1 - zj[lj * 2 + 1];
                    lat_diff[rowbase + gj] = sqrtf(fmaf(d0, d0, d1 * d1));
                }
            }
        }
    }
}

// ---------------------------------------------------------------------------
extern "C" void kernel_launch(void* const* d_in, const int* in_sizes, int n_in,
                              void* d_out, int out_size, void* d_ws, size_t ws_size,
                              hipStream_t stream)
{
    const float* x       = (const float*)d_in[0];
    const float* fc1_w   = (const float*)d_in[1];
    const float* fc1_b   = (const float*)d_in[2];
    const float* fc11_w  = (const float*)d_in[3];
    const float* fc11_b  = (const float*)d_in[4];
    const float* fc12_w  = (const float*)d_in[5];
    const float* fc12_b  = (const float*)d_in[6];
    const float* fc2_w   = (const float*)d_in[7];
    const float* fc2_b   = (const float*)d_in[8];
    const float* fc3_w   = (const float*)d_in[9];
    const float* fc3_b   = (const float*)d_in[10];
    const float* fc31_w  = (const float*)d_in[11];
    const float* fc31_b  = (const float*)d_in[12];
    const float* fc32_w  = (const float*)d_in[13];
    const float* fc32_b  = (const float*)d_in[14];
    const float* fc4_w   = (const float*)d_in[15];
    const float* fc4_b   = (const float*)d_in[16];

    float* out = (float*)d_out;
    float* y        = out;                 // 4096*784
    float* in_diff  = out + 3211264;       // 8386560
    float* lat_diff = out + 11597824;      // 8386560
    float* out_diff = out + 19984384;      // 8386560
    float* z        = out + 28370944;      // 4096*2

    // ---- workspace layout (proven) ----
    float* ws   = (float*)d_ws;
    float* h2   = ws;                          // 4096*200 f32
    float* h3u  = h2  + (size_t)4096 * 200;
    float* y1u  = h3u + (size_t)4096 * 50;
    float* sqx  = y1u + (size_t)4096 * 50;     // 4096
    float* sqy  = sqx + 4096;                  // 4096
    short* xs   = (short*)(sqy + 4096);        // 4096*1600
    short* ys   = xs  + (size_t)NB * 1600;     // 4096*800 used (region 1600)
    short* w1s  = ys  + (size_t)NB * 1600;     // 512*1600
    short* w11s = w1s  + (size_t)512 * 1600;   // 256*832
    short* w32s = w11s + (size_t)256 * 832;    // 512*448
    short* w4s  = w32s + (size_t)512 * 448;    // 896*832
    short* h1s  = w4s  + (size_t)896 * 832;    // 4096*832
    short* y3s  = h1s;                         // alias: h1s dead after fc11
    short* y2s  = h1s  + (size_t)4096 * 832;   // 4096*448

    const dim3 blk(256);

    // 1. prep: weight splits + x split/rowsq(rounded) + sqy zero
    prep_all<<<dim3(8016), blk, 0, stream>>>(
        fc1_w, fc11_w, fc32_w, fc4_w, w1s, w11s, w32s, w4s, x, xs, sqx, sqy);
    // 2. fc1 (256 blocks)
    gemm3_64<1, false, true, false, false><<<dim3(4, 64), blk, 0, stream>>>(
        xs, w1s, fc1_b, nullptr, h1s, 400, 800, 25, 416, nullptr);
    // 3. fc1_1 (128 blocks)
    gemm3_64<1, true, false, false, false><<<dim3(2, 64), blk, 0, stream>>>(
        h1s, w11s, fc11_b, h2, nullptr, 200, 416, 13, 0, nullptr);
    // 4. fused mid-chain
    fused_mid<<<dim3(256), blk, 0, stream>>>(
        h2, fc12_w, fc12_b, fc2_w, fc2_b, fc3_w, fc3_b, fc31_w, fc31_b, z, y2s);
    // 5. fc3_2 (256 blocks)
    gemm3_64<1, false, true, false, false><<<dim3(4, 64), blk, 0, stream>>>(
        y2s, w32s, fc32_b, nullptr, y3s, 400, 224, 7, 416, nullptr);
    // 6. fc4 -> y + ys(hi-only, stride 800) + sqy(from rounded y) (448 blocks)
    gemm3_64<2, true, true, true, true><<<dim3(7, 64), blk, 0, stream>>>(
        y3s, w4s, fc4_b, y, ys, 784, 416, 13, 800, sqy);
    // 7. pdist: y-hh 256^2 + x-hh 256^2 + z
    pdist256<<<dim3(800), dim3(512), 0, stream>>>(
        xs, ys, sqx, sqy, z, in_diff, out_diff, lat_diff);
}

// Round 20
// 208.600 us; speedup vs baseline: 1.0968x; 1.0968x over previous
//
#include <hip/hip_runtime.h>
#include <math.h>

#define NB 4096            // batch
#define DIMX 784           // feature dim for x / y pdists

typedef __attribute__((ext_vector_type(8))) short bf16x8;
typedef __attribute__((ext_vector_type(4))) float f32x4;

__device__ __forceinline__ float lrelu_f(float v) { return v >= 0.f ? v : 0.01f * v; }

// round-to-nearest-even fp32 -> bf16 hi (returned as float), residual -> bf16 lo
__device__ __forceinline__ float split1h(float x, short& hi_s, short& lo_s) {
    unsigned u = __float_as_uint(x);
    unsigned hib = (u + 0x7FFFu + ((u >> 16) & 1u)) & 0xFFFF0000u;
    float hif = __uint_as_float(hib);
    float lo = x - hif;
    unsigned ul = __float_as_uint(lo);
    unsigned lob = (ul + 0x7FFFu + ((ul >> 16) & 1u)) >> 16;
    hi_s = (short)(hib >> 16);
    lo_s = (short)lob;
    return hif;
}

#define GLL(srcp, dstp) __builtin_amdgcn_global_load_lds( \
    (const __attribute__((address_space(1))) void*)(srcp), \
    (__attribute__((address_space(3))) void*)(dstp), 16, 0, 0)

// T2 swizzle (both-sides involution keyed on (row>>1)&3):
//   stage-source col-block (tid&3)^((tid>>3)&3)  [row = tid>>2]
//   read k-slot (lane>>4)^((lane>>1)&3)          [row = 16-aligned + (lane&15)]
// r19 lesson: 256^2 tiles at 1 blk/CU lose the 4-blk/CU co-residency that
// actually hides the 2-phase pipeline latency — keep 128^2 + (256,4).

// ---------------------------------------------------------------------------
// Prep: [0,3920) weight splits; [3920,8016) x-row split + sqx(from hi) + sqy=0.
// sqx = squared norm of bf16-ROUNDED x row -> hh pdist is exact metric on
// rounded points (error <= ||lo_i||+||lo_j|| ~ 0.03 << threshold).
// ---------------------------------------------------------------------------
__global__ __launch_bounds__(256) void prep_all(
    const float* __restrict__ w1, const float* __restrict__ w11,
    const float* __restrict__ w32, const float* __restrict__ w4,
    short* __restrict__ o1, short* __restrict__ o11,
    short* __restrict__ o32, short* __restrict__ o4,
    const float* __restrict__ X, short* __restrict__ Xs,
    float* __restrict__ sqx, float* __restrict__ sqy)
{
    const int bid = blockIdx.x;
    const int t = threadIdx.x;
    if (bid < 3920) {
        const float* W; short* O; int N, K, NP, KP, base;
        if (bid < 1600)      { W = w1;  O = o1;  N = 400; K = 784; NP = 512; KP = 800; base = 0; }
        else if (bid < 2016) { W = w11; O = o11; N = 200; K = 400; NP = 256; KP = 416; base = 1600; }
        else if (bid < 2464) { W = w32; O = o32; N = 400; K = 200; NP = 512; KP = 224; base = 2016; }
        else                 { W = w4;  O = o4;  N = 784; K = 400; NP = 896; KP = 416; base = 2464; }
        const int idx = (bid - base) * 256 + t;
        if (idx >= NP * KP) return;
        const int r = idx / KP, k = idx - r * KP;
        short hi = 0, lo = 0;
        if (r < N && k < K) split1h(W[(size_t)r * K + k], hi, lo);
        O[(size_t)r * 2 * KP + k]      = hi;
        O[(size_t)r * 2 * KP + KP + k] = lo;
    } else {
        const int r = bid - 3920;
        float s = 0.f;
        if (t < 200) {
            const int k0 = t * 4;
            short h[4] = {0, 0, 0, 0}, l[4] = {0, 0, 0, 0};
            if (k0 < 784) {
                float4 v = *(const float4*)(X + (size_t)r * 784 + k0);
                float h0 = split1h(v.x, h[0], l[0]);
                float h1 = split1h(v.y, h[1], l[1]);
                float h2v = split1h(v.z, h[2], l[2]);
                float h3v = split1h(v.w, h[3], l[3]);
                s = h0 * h0 + h1 * h1 + h2v * h2v + h3v * h3v;   // norm of ROUNDED row
            }
            *(uint2*)&Xs[(size_t)r * 1600 + k0]       = *(const uint2*)h;
            *(uint2*)&Xs[(size_t)r * 1600 + 800 + k0] = *(const uint2*)l;
        }
        __shared__ float red[256];
        red[t] = s;
        __syncthreads();
        for (int off = 128; off > 0; off >>= 1) {
            if (t < off) red[t] += red[t + off];
            __syncthreads();
        }
        if (t == 0) { sqx[r] = red[0]; sqy[r] = 0.f; }
    }
}

// ---------------------------------------------------------------------------
// bf16-split MFMA GEMM, 3-TERM, BM=64 x BN=128 tile (r15-proven).
// HIONLY: split output is hi-only [M][KPo]. WROWSQ: |round(y)|^2 -> sqy.
// ---------------------------------------------------------------------------
template<int ACT, bool WF32, bool WSPLIT, bool WROWSQ, bool HIONLY>
__global__ __launch_bounds__(256) void gemm3_64(
    const short* __restrict__ As_g, const short* __restrict__ Ws_g,
    const float* __restrict__ bias, float* __restrict__ C,
    short* __restrict__ Cs, int N, int KPi, int nchunk, int KPo,
    float* __restrict__ sqy)
{
    __shared__ short L[2][12288];   // 48 KiB: Ah@0 Al@2048 Bh@4096 Bl@8192
    const int tid = threadIdx.x;
    const int w = tid >> 6, lane = tid & 63;
    const int wc = w;
    const int m0 = blockIdx.y * 64, n0 = blockIdx.x * 128;
    const int frow = lane & 15;
    const int fk_sw = (((lane >> 4) ^ ((lane >> 1) & 3))) * 8;
    const int srow = tid >> 2;
    const int scol_sw = (((tid & 3) ^ ((tid >> 3) & 3))) * 8;
    const int RS = 2 * KPi;
    const int ld0 = w * 512;

    const short* gA  = As_g + (size_t)(m0 + srow) * RS + scol_sw;
    const short* gB0 = Ws_g + (size_t)(n0 + srow) * RS + scol_sw;
    const short* gB1 = gB0 + (size_t)64 * RS;

    f32x4 acc[4][2] = {};

    auto stage = [&](int buf, int km) {
        GLL(gA  + km,       &L[buf][ld0]);
        GLL(gA  + KPi + km, &L[buf][2048 + ld0]);
        GLL(gB0 + km,       &L[buf][4096 + ld0]);
        GLL(gB1 + km,       &L[buf][6144 + ld0]);
        GLL(gB0 + KPi + km, &L[buf][8192 + ld0]);
        GLL(gB1 + KPi + km, &L[buf][10240 + ld0]);
    };

    stage(0, 0);
    asm volatile("s_waitcnt vmcnt(0)" ::: "memory");
    __builtin_amdgcn_s_barrier();
    int buf = 0;
    #pragma unroll 1
    for (int cc = 0; cc < nchunk; ++cc) {
        if (cc + 1 < nchunk) {
            stage(buf ^ 1, (cc + 1) * 32);
            asm volatile("s_waitcnt vmcnt(6)" ::: "memory");
        } else {
            asm volatile("s_waitcnt vmcnt(0)" ::: "memory");
        }
        __builtin_amdgcn_s_barrier();

        bf16x8 ah[4], al[4], bh[2], bl[2];
        #pragma unroll
        for (int m = 0; m < 4; ++m) {
            const int ro = (m * 16 + frow) * 32 + fk_sw;
            ah[m] = *(const bf16x8*)&L[buf][ro];
            al[m] = *(const bf16x8*)&L[buf][2048 + ro];
        }
        #pragma unroll
        for (int n = 0; n < 2; ++n) {
            const int ro = (wc * 32 + n * 16 + frow) * 32 + fk_sw;
            bh[n] = *(const bf16x8*)&L[buf][4096 + ro];
            bl[n] = *(const bf16x8*)&L[buf][8192 + ro];
        }
        __builtin_amdgcn_s_setprio(1);
        #pragma unroll
        for (int m = 0; m < 4; ++m)
            #pragma unroll
            for (int n = 0; n < 2; ++n) {
                acc[m][n] = __builtin_amdgcn_mfma_f32_16x16x32_bf16(ah[m], bh[n], acc[m][n], 0, 0, 0);
                acc[m][n] = __builtin_amdgcn_mfma_f32_16x16x32_bf16(ah[m], bl[n], acc[m][n], 0, 0, 0);
                acc[m][n] = __builtin_amdgcn_mfma_f32_16x16x32_bf16(al[m], bh[n], acc[m][n], 0, 0, 0);
            }
        __builtin_amdgcn_s_setprio(0);
        __builtin_amdgcn_s_barrier();
        buf ^= 1;
    }

    const int col0 = lane & 15;
    const int row4 = (lane >> 4) * 4;

    float* rowsum = (float*)&L[0][0];
    if (WROWSQ) {
        __syncthreads();
        if (tid < 64) rowsum[tid] = 0.f;
        __syncthreads();
    }

    #pragma unroll
    for (int m = 0; m < 4; ++m) {
        #pragma unroll
        for (int r = 0; r < 4; ++r) {
            const int gm = m0 + m * 16 + row4 + r;
            float vsq = 0.f;
            #pragma unroll
            for (int n = 0; n < 2; ++n) {
                const int gn = n0 + wc * 32 + n * 16 + col0;
                float v = 0.f;
                if (gn < N) {
                    v = acc[m][n][r] + bias[gn];
                    if (ACT == 1)      v = lrelu_f(v);
                    else if (ACT == 2) v = 1.f / (1.f + expf(-v));
                }
                if (WF32 && gn < N) C[(size_t)gm * N + gn] = v;
                if (WSPLIT && gn < KPo) {
                    short hi, lo;
                    float hif = split1h(v, hi, lo);
                    if (HIONLY) {
                        Cs[(size_t)gm * KPo + gn] = hi;
                    } else {
                        Cs[(size_t)gm * 2 * KPo + gn]       = hi;
                        Cs[(size_t)gm * 2 * KPo + KPo + gn] = lo;
                    }
                    if (WROWSQ) vsq = fmaf(hif, hif, vsq);
                }
            }
            if (WROWSQ) atomicAdd(&rowsum[m * 16 + row4 + r], vsq);
        }
    }
    if (WROWSQ) {
        __syncthreads();
        if (tid < 64) atomicAdd(&sqy[m0 + tid], rowsum[tid]);
    }
}

// ---------------------------------------------------------------------------
// Fused mid-chain: h2 -> h3 -> z -> y1 -> y2s (r10-proven)
// ---------------------------------------------------------------------------
__global__ __launch_bounds__(256) void fused_mid(
    const float* __restrict__ h2, const float* __restrict__ W12,
    const float* __restrict__ b12, const float* __restrict__ W2,
    const float* __restrict__ b2,  const float* __restrict__ W3,
    const float* __restrict__ b3,  const float* __restrict__ W31,
    const float* __restrict__ b31, float* __restrict__ z_out,
    short* __restrict__ y2s)
{
    __shared__ float wbuf[200 * 51];
    __shared__ float hl[16 * 201];
    __shared__ float h3l[16 * 51];
    __shared__ float y1l[16 * 51];
    __shared__ float zl[16 * 2];
    __shared__ float w2l[100], w3l[100];
    __shared__ float b12l[50], b2l[2], b3l[50], b31l[200];
    const int t = threadIdx.x;
    const int r0 = blockIdx.x * 16;

    for (int i = t; i < 50 * 200; i += 256) { int n = i / 200, k = i - n * 200; wbuf[n * 201 + k] = W12[i]; }
    for (int i = t; i < 16 * 200; i += 256) { int r = i / 200, k = i - r * 200; hl[r * 201 + k] = h2[(size_t)(r0 + r) * 200 + k]; }
    for (int i = t; i < 100; i += 256) { w2l[i] = W2[i]; w3l[i] = W3[i]; }
    if (t < 50)  { b12l[t] = b12[t]; b3l[t] = b3[t]; }
    if (t < 2)   b2l[t] = b2[t];
    if (t < 200) b31l[t] = b31[t];
    __syncthreads();

    for (int i = t; i < 16 * 50; i += 256) {
        int r = i / 50, n = i - r * 50;
        float s = b12l[n];
        #pragma unroll 4
        for (int k = 0; k < 200; ++k) s = fmaf(hl[r * 201 + k], wbuf[n * 201 + k], s);
        h3l[r * 51 + n] = tanhf(lrelu_f(s));
    }
    __syncthreads();

    if (t < 32) {
        int r = t >> 1, n = t & 1;
        float s = b2l[n];
        #pragma unroll
        for (int k = 0; k < 50; ++k) s = fmaf(h3l[r * 51 + k], w2l[n * 50 + k], s);
        zl[r * 2 + n] = s;
        z_out[(size_t)(r0 + r) * 2 + n] = s;
    }
    for (int i = t; i < 200 * 50; i += 256) { int n = i / 50, k = i - n * 50; wbuf[n * 51 + k] = W31[i]; }
    __syncthreads();

    for (int i = t; i < 16 * 50; i += 256) {
        int r = i / 50, n = i - r * 50;
        float s = fmaf(zl[r * 2], w3l[n * 2], fmaf(zl[r * 2 + 1], w3l[n * 2 + 1], b3l[n]));
        y1l[r * 51 + n] = lrelu_f(s);
    }
    __syncthreads();

    for (int i = t; i < 16 * 224; i += 256) {
        int r = i / 224, n = i - r * 224;
        float v = 0.f;
        if (n < 200) {
            float s = b31l[n];
            #pragma unroll
            for (int k = 0; k < 50; ++k) s = fmaf(y1l[r * 51 + k], wbuf[n * 51 + k], s);
            v = lrelu_f(s);
        }
        short hi, lo;
        split1h(v, hi, lo);
        const size_t gm = r0 + r;
        y2s[gm * 448 + n]       = hi;
        y2s[gm * 448 + 224 + n] = lo;
    }
}

// ---------------------------------------------------------------------------
// Final mega pdist, 1584 blocks x 256 thr, 32 KiB LDS, 4 blk/CU (r18-proven):
//   blocks 0..527    : y-side hh (ys stride 800, sqy from rounded y)
//   blocks 528..1055 : x-side hh (xs stride 1600 [hi|lo], sqx from rounded x)
//   blocks 1056..1583: z-side direct difference
// hh + rounded-norms = exact metric on bf16-rounded points.
// Unified double-buffered + vmcnt(4) body. (256,5) spills -> keep (256,4).
// ---------------------------------------------------------------------------
__global__ __launch_bounds__(256, 4) void pdist_all(
    const short* __restrict__ xs, const short* __restrict__ ys,
    const float* __restrict__ sqx, const float* __restrict__ sqy,
    const float* __restrict__ Z, float* __restrict__ in_diff,
    float* __restrict__ out_diff, float* __restrict__ lat_diff)
{
    __shared__ short L[4][4096];   // 32 KiB
    const int tid = threadIdx.x;
    const int orig = blockIdx.x;

    if (orig < 1056) {
        // ================= unified hh pdist tile =================
        const bool isY = (orig < 528);
        const int o = isY ? orig : orig - 528;
        const int b = (o & 7) * 66 + (o >> 3);     // bijective: 528 = 8*66
        int rem = b, ti = 0;
        while (rem >= 32 - ti) { rem -= 32 - ti; ++ti; }
        const int tj = ti + rem;

        const short* Xs = isY ? ys : xs;
        const int rs    = isY ? 800 : 1600;
        const float* sq = isY ? sqy : sqx;
        float* outp     = isY ? out_diff : in_diff;

        const int w = tid >> 6, lane = tid & 63;
        const int wr = w >> 1, wc = w & 1;
        const int frow = lane & 15;
        const int fk_sw = (((lane >> 4) ^ ((lane >> 1) & 3))) * 8;
        const int srow = tid >> 2;
        const int scol_sw = (((tid & 3) ^ ((tid >> 3) & 3))) * 8;
        const int i0 = ti * 128, j0 = tj * 128;
        const int ld0 = w * 512;

        const short* gA = Xs + (size_t)(i0 + srow) * rs + scol_sw;
        const short* gB = Xs + (size_t)(j0 + srow) * rs + scol_sw;
        const size_t half = (size_t)64 * rs;

        f32x4 acc[4][4] = {};

        auto stage = [&](int buf, int km) {
            short* dA = buf ? &L[2][0] : &L[0][0];
            short* dB = buf ? &L[3][0] : &L[1][0];
            GLL(gA + km,        dA + ld0);   GLL(gA + half + km, dA + 2048 + ld0);
            GLL(gB + km,        dB + ld0);   GLL(gB + half + km, dB + 2048 + ld0);
        };

        stage(0, 0);
        asm volatile("s_waitcnt vmcnt(0)" ::: "memory");
        __builtin_amdgcn_s_barrier();
        int buf = 0;
        #pragma unroll 1
        for (int cc = 0; cc < 25; ++cc) {
            if (cc < 24) {
                stage(buf ^ 1, (cc + 1) * 32);
                asm volatile("s_waitcnt vmcnt(4)" ::: "memory");
            } else {
                asm volatile("s_waitcnt vmcnt(0)" ::: "memory");
            }
            __builtin_amdgcn_s_barrier();

            const short* SA = buf ? &L[2][0] : &L[0][0];
            const short* SB = buf ? &L[3][0] : &L[1][0];
            bf16x8 a[4], bb[4];
            #pragma unroll
            for (int m = 0; m < 4; ++m)
                a[m] = *(const bf16x8*)&SA[(wr * 64 + m * 16 + frow) * 32 + fk_sw];
            #pragma unroll
            for (int n = 0; n < 4; ++n)
                bb[n] = *(const bf16x8*)&SB[(wc * 64 + n * 16 + frow) * 32 + fk_sw];
            __builtin_amdgcn_s_setprio(1);
            #pragma unroll
            for (int m = 0; m < 4; ++m)
                #pragma unroll
                for (int n = 0; n < 4; ++n)
                    acc[m][n] = __builtin_amdgcn_mfma_f32_16x16x32_bf16(a[m], bb[n], acc[m][n], 0, 0, 0);
            __builtin_amdgcn_s_setprio(0);
            __builtin_amdgcn_s_barrier();
            buf ^= 1;
        }

        const int col0 = lane & 15;
        const int row4 = (lane >> 4) * 4;
        float sqj_v[4];
        #pragma unroll
        for (int n = 0; n < 4; ++n)
            sqj_v[n] = sq[j0 + wc * 64 + n * 16 + col0];
        #pragma unroll
        for (int m = 0; m < 4; ++m) {
            #pragma unroll
            for (int r = 0; r < 4; ++r) {
                const int gi = i0 + wr * 64 + m * 16 + row4 + r;
                const float sqi = sq[gi];
                const int rowbase = (gi * (2 * NB - 1 - gi)) / 2 - gi - 1;
                #pragma unroll
                for (int n = 0; n < 4; ++n) {
                    const int gj = j0 + wc * 64 + n * 16 + col0;
                    if (gj > gi) {
                        float d2 = sqi + sqj_v[n] - 2.f * acc[m][n][r];
                        outp[rowbase + gj] = sqrtf(fmaxf(d2, 0.f));
                    }
                }
            }
        }
    } else {
        // ================= z-pdist: direct difference =================
        const int o = orig - 1056;
        const int b = (o & 7) * 66 + (o >> 3);
        int rem = b, ti = 0;
        while (rem >= 32 - ti) { rem -= 32 - ti; ++ti; }
        const int tj = ti + rem;
        const int i0 = ti * 128, j0 = tj * 128;

        float* zi = (float*)&L[0][0];
        float* zj = (float*)&L[0][512];
        if (tid < 128) {
            *(float2*)&zi[tid * 2] = *(const float2*)&Z[(size_t)(i0 + tid) * 2];
        } else {
            const int r = tid - 128;
            *(float2*)&zj[r * 2] = *(const float2*)&Z[(size_t)(j0 + r) * 2];
        }
        __syncthreads();

        const int ty = tid >> 4;
        const int tx = tid & 15;
        #pragma unroll
        for (int ii = 0; ii < 8; ++ii) {
            const int li = ty * 8 + ii;
            const int gi = i0 + li;
            const int rowbase = (gi * (2 * NB - 1 - gi)) / 2 - gi - 1;
            const float zi0 = zi[li * 2], zi1 = zi[li * 2 + 1];
            #pragma unroll
            for (int jj = 0; jj < 8; ++jj) {
                const int lj = tx * 8 + jj;
                const int gj = j0 + lj;
                if (gj > gi) {
                    float d0 = zi0 - zj[lj * 2];
                    float d1 = zi1 - zj[lj * 2 + 1];
                    lat_diff[rowbase + gj] = sqrtf(fmaf(d0, d0, d1 * d1));
                }
            }
        }
    }
}

// ---------------------------------------------------------------------------
extern "C" void kernel_launch(void* const* d_in, const int* in_sizes, int n_in,
                              void* d_out, int out_size, void* d_ws, size_t ws_size,
                              hipStream_t stream)
{
    const float* x       = (const float*)d_in[0];
    const float* fc1_w   = (const float*)d_in[1];
    const float* fc1_b   = (const float*)d_in[2];
    const float* fc11_w  = (const float*)d_in[3];
    const float* fc11_b  = (const float*)d_in[4];
    const float* fc12_w  = (const float*)d_in[5];
    const float* fc12_b  = (const float*)d_in[6];
    const float* fc2_w   = (const float*)d_in[7];
    const float* fc2_b   = (const float*)d_in[8];
    const float* fc3_w   = (const float*)d_in[9];
    const float* fc3_b   = (const float*)d_in[10];
    const float* fc31_w  = (const float*)d_in[11];
    const float* fc31_b  = (const float*)d_in[12];
    const float* fc32_w  = (const float*)d_in[13];
    const float* fc32_b  = (const float*)d_in[14];
    const float* fc4_w   = (const float*)d_in[15];
    const float* fc4_b   = (const float*)d_in[16];

    float* out = (float*)d_out;
    float* y        = out;                 // 4096*784
    float* in_diff  = out + 3211264;       // 8386560
    float* lat_diff = out + 11597824;      // 8386560
    float* out_diff = out + 19984384;      // 8386560
    float* z        = out + 28370944;      // 4096*2

    // ---- workspace layout (proven; ys region kept at 1600 shorts/row,
    //      only [NB][800] hi used now) ----
    float* ws   = (float*)d_ws;
    float* h2   = ws;                          // 4096*200 f32
    float* h3u  = h2  + (size_t)4096 * 200;
    float* y1u  = h3u + (size_t)4096 * 50;
    float* sqx  = y1u + (size_t)4096 * 50;     // 4096
    float* sqy  = sqx + 4096;                  // 4096
    short* xs   = (short*)(sqy + 4096);        // 4096*1600
    short* ys   = xs  + (size_t)NB * 1600;     // 4096*800 used (region 1600)
    short* w1s  = ys  + (size_t)NB * 1600;     // 512*1600
    short* w11s = w1s  + (size_t)512 * 1600;   // 256*832
    short* w32s = w11s + (size_t)256 * 832;    // 512*448
    short* w4s  = w32s + (size_t)512 * 448;    // 896*832
    short* h1s  = w4s  + (size_t)896 * 832;    // 4096*832
    short* y3s  = h1s;                         // alias: h1s dead after fc11
    short* y2s  = h1s  + (size_t)4096 * 832;   // 4096*448

    const dim3 blk(256);

    // 1. prep: weight splits + x split/rowsq(rounded) + sqy zero
    prep_all<<<dim3(8016), blk, 0, stream>>>(
        fc1_w, fc11_w, fc32_w, fc4_w, w1s, w11s, w32s, w4s, x, xs, sqx, sqy);
    // 2. fc1 (256 blocks)
    gemm3_64<1, false, true, false, false><<<dim3(4, 64), blk, 0, stream>>>(
        xs, w1s, fc1_b, nullptr, h1s, 400, 800, 25, 416, nullptr);
    // 3. fc1_1 (128 blocks)
    gemm3_64<1, true, false, false, false><<<dim3(2, 64), blk, 0, stream>>>(
        h1s, w11s, fc11_b, h2, nullptr, 200, 416, 13, 0, nullptr);
    // 4. fused mid-chain
    fused_mid<<<dim3(256), blk, 0, stream>>>(
        h2, fc12_w, fc12_b, fc2_w, fc2_b, fc3_w, fc3_b, fc31_w, fc31_b, z, y2s);
    // 5. fc3_2 (256 blocks)
    gemm3_64<1, false, true, false, false><<<dim3(4, 64), blk, 0, stream>>>(
        y2s, w32s, fc32_b, nullptr, y3s, 400, 224, 7, 416, nullptr);
    // 6. fc4 -> y + ys(hi-only, stride 800) + sqy(from rounded y) (448 blocks)
    gemm3_64<2, true, true, true, true><<<dim3(7, 64), blk, 0, stream>>>(
        y3s, w4s, fc4_b, y, ys, 784, 416, 13, 800, sqy);
    // 7. mega pdist: y-hh + x-hh + z (metric on rounded points)
    pdist_all<<<dim3(1584), blk, 0, stream>>>(
        xs, ys, sqx, sqy, z, in_diff, out_diff, lat_diff);
}